// Round 2
// baseline (356.436 us; speedup 1.0000x reference)
//
#include <hip/hip_runtime.h>

#define NB 64
#define NS 2048
#define ND 512
#define K  16                 // timesteps per wave run
#define WPB 4                 // waves per block
#define GPB (NS / K / WPB)    // blocks per batch = 32
#define NRUN (NS / K)         // runs (chunk-maxes) per batch = 128
#define RW4 (ND / 4)          // float4s per row = 128

// Kernel 1: each wave owns K consecutive timesteps of one batch, full D width.
// Lane-contiguous mapping: lane holds float4 #lane and #(lane+64) of the row,
// so every global_load_dwordx4 covers a contiguous 1 KB (16 cache lines), not
// a 2 KB strided span. Previous row stays in registers; 1-row software
// prefetch with peeled last iteration keeps loads in flight across compute.
__global__ __launch_bounds__(256, 8) void l2_dist_kernel(const float* __restrict__ x,
                                                         float* __restrict__ out,
                                                         float* __restrict__ runmax) {
    const int b    = blockIdx.y;
    const int wave = threadIdx.x >> 6;
    const int lane = threadIdx.x & 63;
    const int g    = blockIdx.x * WPB + wave;   // run index within batch (0..127)
    const int s0   = g * K;

    const float4* row  = (const float4*)(x + (size_t)b * NS * ND) + (size_t)s0 * RW4 + lane;
    const float4* prow = (s0 > 0) ? row - RW4 : row;   // s0==0 -> d[0]=0 branchlessly

    float4 p0 = prow[0];
    float4 p1 = prow[64];
    float4 c0 = row[0];
    float4 c1 = row[64];

    float wmax = 0.0f;
    float myd  = 0.0f;   // lane i keeps row i's sum -> coalesced store at end

    #pragma unroll 5
    for (int i = 0; i < K - 1; ++i) {
        const float4* nrow = row + (size_t)(i + 1) * RW4;
        float4 n0 = nrow[0];
        float4 n1 = nrow[64];

        float dx, sum = 0.0f;
        dx = c0.x - p0.x; sum += dx * dx;
        dx = c0.y - p0.y; sum += dx * dx;
        dx = c0.z - p0.z; sum += dx * dx;
        dx = c0.w - p0.w; sum += dx * dx;
        dx = c1.x - p1.x; sum += dx * dx;
        dx = c1.y - p1.y; sum += dx * dx;
        dx = c1.z - p1.z; sum += dx * dx;
        dx = c1.w - p1.w; sum += dx * dx;

        #pragma unroll
        for (int m = 32; m >= 1; m >>= 1)
            sum += __shfl_xor(sum, m, 64);

        wmax = fmaxf(wmax, sum);
        myd  = (lane == i) ? sum : myd;

        p0 = c0; p1 = c1; c0 = n0; c1 = n1;
    }

    // peeled last row (no prefetch)
    {
        float dx, sum = 0.0f;
        dx = c0.x - p0.x; sum += dx * dx;
        dx = c0.y - p0.y; sum += dx * dx;
        dx = c0.z - p0.z; sum += dx * dx;
        dx = c0.w - p0.w; sum += dx * dx;
        dx = c1.x - p1.x; sum += dx * dx;
        dx = c1.y - p1.y; sum += dx * dx;
        dx = c1.z - p1.z; sum += dx * dx;
        dx = c1.w - p1.w; sum += dx * dx;

        #pragma unroll
        for (int m = 32; m >= 1; m >>= 1)
            sum += __shfl_xor(sum, m, 64);

        wmax = fmaxf(wmax, sum);
        myd  = (lane == K - 1) ? sum : myd;
    }

    if (lane < K) out[(size_t)b * NS + s0 + lane] = myd;   // one coalesced 64B store
    if (lane == 0) runmax[b * NRUN + g] = wmax;            // private slot, no atomics
}

// Kernel 2: reduce the 128 run-maxes per batch, normalize row in place.
// grid = (2, 64); each block handles 1024 floats (one float4 per thread).
__global__ __launch_bounds__(256) void l2_norm_kernel(float* __restrict__ out,
                                                      const float* __restrict__ runmax) {
    const int b    = blockIdx.y;
    const int half = blockIdx.x;
    const int tid  = threadIdx.x;

    __shared__ float smax;
    if (tid < 64) {  // wave 0: butterfly-max over the 128 run maxes
        float v = fmaxf(runmax[b * NRUN + tid], runmax[b * NRUN + 64 + tid]);
        #pragma unroll
        for (int m = 32; m >= 1; m >>= 1)
            v = fmaxf(v, __shfl_xor(v, m, 64));
        if (tid == 0) smax = v;
    }
    __syncthreads();
    const float inv = 1.0f / smax;

    float4* rowp = (float4*)(out + (size_t)b * NS) + half * 256 + tid;
    float4 v = *rowp;
    v.x *= inv; v.y *= inv; v.z *= inv; v.w *= inv;
    *rowp = v;
}

extern "C" void kernel_launch(void* const* d_in, const int* in_sizes, int n_in,
                              void* d_out, int out_size, void* d_ws, size_t ws_size,
                              hipStream_t stream) {
    const float* x = (const float*)d_in[0];
    float* out     = (float*)d_out;
    float* runmax  = (float*)d_ws;  // 64*128 floats, fully overwritten by k1

    l2_dist_kernel<<<dim3(GPB, NB), dim3(256), 0, stream>>>(x, out, runmax);
    l2_norm_kernel<<<dim3(2, NB), dim3(256), 0, stream>>>(out, runmax);
}